// Round 1
// baseline (2942.856 us; speedup 1.0000x reference)
//
#include <hip/hip_runtime.h>

#define NPTS 200000
#define CIN 128
#define COUT 256
#define TAPS 62        // Wm[k] == 0 for k >= 62 (mask in setup) -> skip exactly
#define KNE 125

typedef __attribute__((ext_vector_type(8))) short bf16x8;   // 8 bf16 in 4 VGPRs
typedef __attribute__((ext_vector_type(4))) float f32x4;

static __device__ __forceinline__ unsigned short f2bf(float f) {
    unsigned int u = __builtin_bit_cast(unsigned int, f);
    u = (u + 0x7fffu + ((u >> 16) & 1u)) >> 16;   // RNE
    return (unsigned short)u;
}

static __device__ __forceinline__ bf16x8 ld8(const unsigned short* p) {
    return *reinterpret_cast<const bf16x8*>(p);
}

// ---------------- prep: feats f32 -> bf16, plus zero row at index NPTS ----------------
__global__ void k_cast_feats(const float* __restrict__ src, unsigned short* __restrict__ dst) {
    const long long total4 = (long long)(NPTS + 1) * CIN / 4;
    for (long long i = (long long)blockIdx.x * blockDim.x + threadIdx.x; i < total4;
         i += (long long)gridDim.x * blockDim.x) {
        long long e = i * 4;
        float4 v = make_float4(0.f, 0.f, 0.f, 0.f);
        if (e < (long long)NPTS * CIN) v = *reinterpret_cast<const float4*>(src + e);
        ushort4 u;
        u.x = f2bf(v.x); u.y = f2bf(v.y); u.z = f2bf(v.z); u.w = f2bf(v.w);
        *reinterpret_cast<ushort4*>(dst + e) = u;
    }
}

// ---------------- prep: transpose + cast: dst[b][c][r] = (bf16) src[b][r][c] ----------------
// R, C multiples of 64. grid = (R/64, C/64, batch)
__global__ void k_transpose_cast(const float* __restrict__ src, unsigned short* __restrict__ dst,
                                 int R, int C) {
    __shared__ float tile[64][65];
    const float* s = src + (long long)blockIdx.z * R * C;
    unsigned short* d = dst + (long long)blockIdx.z * R * C;
    const int r0 = blockIdx.x * 64, c0 = blockIdx.y * 64;
    const int tid = threadIdx.x;
#pragma unroll
    for (int i = 0; i < 16; ++i) {
        int e = i * 256 + tid;
        int rr = e >> 6, cc = e & 63;
        tile[rr][cc] = s[(long long)(r0 + rr) * C + (c0 + cc)];
    }
    __syncthreads();
#pragma unroll
    for (int i = 0; i < 16; ++i) {
        int e = i * 256 + tid;
        int orr = e >> 6, occ = e & 63;
        d[(long long)(c0 + orr) * R + (r0 + occ)] = f2bf(tile[occ][orr]);
    }
}

// ---------------- ctx GEMM: ctx[n] = bm + sum_t feats_b[nidx[n,t]] @ WmT[t] ----------------
// block = 256 thr (4 waves, 2x2), wave tile 64x64, block tile 128(M) x 128(N).
// A fragments gathered directly from global (per-lane 16B), B fragments from
// pre-transposed wmt[t][o][c] (per-lane 16B contiguous). No LDS, no barriers.
__global__ __launch_bounds__(256) void k_ctx(
    const unsigned short* __restrict__ feats_b,   // (NPTS+1) x 128
    const int* __restrict__ nidx,                 // NPTS x 125
    const unsigned short* __restrict__ wmt,       // 62 x 256 x 128
    const float* __restrict__ bm,                 // 256
    unsigned short* __restrict__ ctx_b)           // 200064 x 256 (bf16)
{
    const int bid = blockIdx.x;
    const int mb = bid >> 1, nb = bid & 1;
    const int m0 = mb * 128, n0 = nb * 128;
    const int lane = threadIdx.x & 63;
    const int w = threadIdx.x >> 6;
    const int wr = w >> 1, wc = w & 1;
    const int wm0 = m0 + wr * 64;
    const int wn0 = n0 + wc * 64;
    const int l15 = lane & 15, lk = lane >> 4;

    f32x4 acc[4][4] = {};

    int bcol[4];
#pragma unroll
    for (int nf = 0; nf < 4; ++nf) bcol[nf] = (wn0 + nf * 16 + l15) * 128 + lk * 8;

    for (int t = 0; t < TAPS; ++t) {
        unsigned aoff[4];
#pragma unroll
        for (int mf = 0; mf < 4; ++mf) {
            int gr = wm0 + mf * 16 + l15;
            int ii = (gr < NPTS) ? nidx[gr * KNE + t] : NPTS;   // NPTS -> zero row
            aoff[mf] = (unsigned)ii * 128 + lk * 8;
        }
        const unsigned short* wt = wmt + t * (256 * 128);
#pragma unroll
        for (int ks = 0; ks < 4; ++ks) {
            bf16x8 a[4], b[4];
#pragma unroll
            for (int mf = 0; mf < 4; ++mf) a[mf] = ld8(feats_b + aoff[mf] + ks * 32);
#pragma unroll
            for (int nf = 0; nf < 4; ++nf) b[nf] = ld8(wt + bcol[nf] + ks * 32);
#pragma unroll
            for (int mf = 0; mf < 4; ++mf)
#pragma unroll
                for (int nf = 0; nf < 4; ++nf)
                    acc[mf][nf] = __builtin_amdgcn_mfma_f32_16x16x32_bf16(a[mf], b[nf], acc[mf][nf], 0, 0, 0);
        }
    }

    // epilogue: + bm, store bf16.  C/D layout: col = lane&15, row = (lane>>4)*4 + j
#pragma unroll
    for (int nf = 0; nf < 4; ++nf) {
        int col = wn0 + nf * 16 + l15;
        float bias = bm[col];
#pragma unroll
        for (int mf = 0; mf < 4; ++mf) {
#pragma unroll
            for (int j = 0; j < 4; ++j) {
                int gr = wm0 + mf * 16 + lk * 4 + j;
                if (gr < NPTS) ctx_b[(long long)gr * 256 + col] = f2bf(acc[mf][nf][j] + bias);
            }
        }
    }
}

// ---------------- MLP: out = (relu(relu(ctx@W0+b0)@W1+b1))@W2+b2 ; split loc / |scale| ----------------
// block = 512 thr (8 waves, 2x4), block tile 128(M) x 256(N), wave tile 64x64.
// Hidden activations round-trip through 64KB LDS with XOR swizzle (elem ^= (row&7)<<3).
__global__ __launch_bounds__(512) void k_mlp(
    const unsigned short* __restrict__ ctx_b,
    const unsigned short* __restrict__ w0t, const float* __restrict__ b0,
    const unsigned short* __restrict__ w1t, const float* __restrict__ b1,
    const unsigned short* __restrict__ w2t, const float* __restrict__ b2,
    float* __restrict__ out)
{
    __shared__ unsigned short hbuf[128 * 256];
    const int m0 = blockIdx.x * 128;
    const int lane = threadIdx.x & 63;
    const int w = threadIdx.x >> 6;
    const int wr = w >> 2, wc = w & 3;
    const int l15 = lane & 15, lk = lane >> 4;
    const int wn0 = wc * 64;
    const int lm0 = wr * 64;
    const int wm0 = m0 + lm0;

    f32x4 acc[4][4];

    // ---- layer 1: A = ctx_b (global), B = w0t
#pragma unroll
    for (int i = 0; i < 4; ++i)
#pragma unroll
        for (int j = 0; j < 4; ++j) acc[i][j] = (f32x4){0.f, 0.f, 0.f, 0.f};
#pragma unroll
    for (int ks = 0; ks < 8; ++ks) {
        bf16x8 a[4], b[4];
#pragma unroll
        for (int mf = 0; mf < 4; ++mf)
            a[mf] = ld8(ctx_b + (long long)(wm0 + mf * 16 + l15) * 256 + lk * 8 + ks * 32);
#pragma unroll
        for (int nf = 0; nf < 4; ++nf)
            b[nf] = ld8(w0t + (wn0 + nf * 16 + l15) * 256 + lk * 8 + ks * 32);
#pragma unroll
        for (int mf = 0; mf < 4; ++mf)
#pragma unroll
            for (int nf = 0; nf < 4; ++nf)
                acc[mf][nf] = __builtin_amdgcn_mfma_f32_16x16x32_bf16(a[mf], b[nf], acc[mf][nf], 0, 0, 0);
    }
#pragma unroll
    for (int nf = 0; nf < 4; ++nf) {
        int col = wn0 + nf * 16 + l15;
        float bias = b0[col];
#pragma unroll
        for (int mf = 0; mf < 4; ++mf)
#pragma unroll
            for (int j = 0; j < 4; ++j) {
                int lr = lm0 + mf * 16 + lk * 4 + j;
                float v = fmaxf(acc[mf][nf][j] + bias, 0.f);
                int e = (lr * 256 + col) ^ ((lr & 7) << 3);
                hbuf[e] = f2bf(v);
            }
    }
    __syncthreads();

    // ---- layer 2: A = hbuf (swizzled), B = w1t
#pragma unroll
    for (int i = 0; i < 4; ++i)
#pragma unroll
        for (int j = 0; j < 4; ++j) acc[i][j] = (f32x4){0.f, 0.f, 0.f, 0.f};
#pragma unroll
    for (int ks = 0; ks < 8; ++ks) {
        bf16x8 a[4], b[4];
#pragma unroll
        for (int mf = 0; mf < 4; ++mf) {
            int lr = lm0 + mf * 16 + l15;
            int e = (lr * 256 + lk * 8 + ks * 32) ^ ((lr & 7) << 3);
            a[mf] = ld8(hbuf + e);
        }
#pragma unroll
        for (int nf = 0; nf < 4; ++nf)
            b[nf] = ld8(w1t + (wn0 + nf * 16 + l15) * 256 + lk * 8 + ks * 32);
#pragma unroll
        for (int mf = 0; mf < 4; ++mf)
#pragma unroll
            for (int nf = 0; nf < 4; ++nf)
                acc[mf][nf] = __builtin_amdgcn_mfma_f32_16x16x32_bf16(a[mf], b[nf], acc[mf][nf], 0, 0, 0);
    }
    __syncthreads();
#pragma unroll
    for (int nf = 0; nf < 4; ++nf) {
        int col = wn0 + nf * 16 + l15;
        float bias = b1[col];
#pragma unroll
        for (int mf = 0; mf < 4; ++mf)
#pragma unroll
            for (int j = 0; j < 4; ++j) {
                int lr = lm0 + mf * 16 + lk * 4 + j;
                float v = fmaxf(acc[mf][nf][j] + bias, 0.f);
                int e = (lr * 256 + col) ^ ((lr & 7) << 3);
                hbuf[e] = f2bf(v);
            }
    }
    __syncthreads();

    // ---- layer 3: A = hbuf, B = w2t, write outputs
#pragma unroll
    for (int i = 0; i < 4; ++i)
#pragma unroll
        for (int j = 0; j < 4; ++j) acc[i][j] = (f32x4){0.f, 0.f, 0.f, 0.f};
#pragma unroll
    for (int ks = 0; ks < 8; ++ks) {
        bf16x8 a[4], b[4];
#pragma unroll
        for (int mf = 0; mf < 4; ++mf) {
            int lr = lm0 + mf * 16 + l15;
            int e = (lr * 256 + lk * 8 + ks * 32) ^ ((lr & 7) << 3);
            a[mf] = ld8(hbuf + e);
        }
#pragma unroll
        for (int nf = 0; nf < 4; ++nf)
            b[nf] = ld8(w2t + (wn0 + nf * 16 + l15) * 256 + lk * 8 + ks * 32);
#pragma unroll
        for (int mf = 0; mf < 4; ++mf)
#pragma unroll
            for (int nf = 0; nf < 4; ++nf)
                acc[mf][nf] = __builtin_amdgcn_mfma_f32_16x16x32_bf16(a[mf], b[nf], acc[mf][nf], 0, 0, 0);
    }
#pragma unroll
    for (int nf = 0; nf < 4; ++nf) {
        int col = wn0 + nf * 16 + l15;
        float bias = b2[col];
#pragma unroll
        for (int mf = 0; mf < 4; ++mf)
#pragma unroll
            for (int j = 0; j < 4; ++j) {
                int gr = wm0 + mf * 16 + lk * 4 + j;
                if (gr < NPTS) {
                    float v = acc[mf][nf][j] + bias;
                    if (col < 128) out[(long long)gr * 128 + col] = v;
                    else out[(long long)NPTS * 128 + (long long)gr * 128 + (col - 128)] = fabsf(v);
                }
            }
    }
}

extern "C" void kernel_launch(void* const* d_in, const int* in_sizes, int n_in,
                              void* d_out, int out_size, void* d_ws, size_t ws_size,
                              hipStream_t stream) {
    const float* feats = (const float*)d_in[0];
    const int*   nidx  = (const int*)d_in[1];
    const float* Wm    = (const float*)d_in[2];
    const float* bm    = (const float*)d_in[3];
    const float* W0    = (const float*)d_in[4];
    const float* b0    = (const float*)d_in[5];
    const float* W1    = (const float*)d_in[6];
    const float* b1    = (const float*)d_in[7];
    const float* W2    = (const float*)d_in[8];
    const float* b2    = (const float*)d_in[9];

    char* ws = (char*)d_ws;
    size_t o = 0;
    unsigned short* feats_b = (unsigned short*)(ws + o); o += (size_t)(NPTS + 1) * CIN * 2;   // 51,200,256
    o = (o + 255) & ~(size_t)255;
    unsigned short* wmt = (unsigned short*)(ws + o); o += (size_t)TAPS * 256 * 128 * 2;       // 4,063,232
    unsigned short* w0t = (unsigned short*)(ws + o); o += 256 * 256 * 2;
    unsigned short* w1t = (unsigned short*)(ws + o); o += 256 * 256 * 2;
    unsigned short* w2t = (unsigned short*)(ws + o); o += 256 * 256 * 2;
    unsigned short* ctx_b = (unsigned short*)(ws + o); o += (size_t)200064 * 256 * 2;         // 102.4 MB

    k_cast_feats<<<2048, 256, 0, stream>>>(feats, feats_b);
    k_transpose_cast<<<dim3(2, 4, TAPS), 256, 0, stream>>>(Wm, wmt, 128, 256);
    k_transpose_cast<<<dim3(4, 4, 1), 256, 0, stream>>>(W0, w0t, 256, 256);
    k_transpose_cast<<<dim3(4, 4, 1), 256, 0, stream>>>(W1, w1t, 256, 256);
    k_transpose_cast<<<dim3(4, 4, 1), 256, 0, stream>>>(W2, w2t, 256, 256);
    k_ctx<<<3126, 256, 0, stream>>>(feats_b, nidx, wmt, bm, ctx_b);
    k_mlp<<<1563, 512, 0, stream>>>(ctx_b, w0t, b0, w1t, b1, w2t, b2, (float*)d_out);
}

// Round 2
// 2364.113 us; speedup vs baseline: 1.2448x; 1.2448x over previous
//
#include <hip/hip_runtime.h>

#define NPTS 200000
#define NP2  200064          // padded row count (multiple of 128)
#define CIN 128
#define COUT 256
#define TAPS 62              // Wm[k] == 0 for k >= 62 (mask in setup) -> skip exactly
#define KNE 125

typedef __attribute__((ext_vector_type(8))) short bf16x8;   // 8 bf16 in 4 VGPRs
typedef __attribute__((ext_vector_type(4))) float f32x4;

static __device__ __forceinline__ unsigned short f2bf(float f) {
    unsigned int u = __builtin_bit_cast(unsigned int, f);
    u = (u + 0x7fffu + ((u >> 16) & 1u)) >> 16;   // RNE
    return (unsigned short)u;
}

static __device__ __forceinline__ bf16x8 ld8(const unsigned short* p) {
    return *reinterpret_cast<const bf16x8*>(p);
}

// async global->LDS, 16B per lane. LDS dest = wave-uniform base + lane*16.
static __device__ __forceinline__ void gload_lds16(const void* g, void* l) {
    __builtin_amdgcn_global_load_lds(
        (const __attribute__((address_space(1))) unsigned int*)g,
        (__attribute__((address_space(3))) unsigned int*)l, 16, 0, 0);
}

// ---------------- prep: feats f32 -> bf16, plus zero row at index NPTS ----------------
__global__ void k_cast_feats(const float* __restrict__ src, unsigned short* __restrict__ dst) {
    const long long total4 = (long long)(NPTS + 1) * CIN / 4;
    for (long long i = (long long)blockIdx.x * blockDim.x + threadIdx.x; i < total4;
         i += (long long)gridDim.x * blockDim.x) {
        long long e = i * 4;
        float4 v = make_float4(0.f, 0.f, 0.f, 0.f);
        if (e < (long long)NPTS * CIN) v = *reinterpret_cast<const float4*>(src + e);
        ushort4 u;
        u.x = f2bf(v.x); u.y = f2bf(v.y); u.z = f2bf(v.z); u.w = f2bf(v.w);
        *reinterpret_cast<ushort4*>(dst + e) = u;
    }
}

// ---------------- prep: nidx transpose: nidx_t[t][n] = nidx[n][t] (pad rows -> NPTS) ----------------
__global__ void k_nidx_t(const int* __restrict__ nidx, int* __restrict__ out) {
    int n = blockIdx.x * 256 + threadIdx.x;
    if (n >= NP2) return;
    if (n < NPTS) {
        const int* row = nidx + (long long)n * KNE;
#pragma unroll 2
        for (int t = 0; t < TAPS; ++t) out[(long long)t * NP2 + n] = row[t];
    } else {
#pragma unroll 2
        for (int t = 0; t < TAPS; ++t) out[(long long)t * NP2 + n] = NPTS;
    }
}

// ---------------- prep: transpose + cast: dst[b][c][r] = (bf16) src[b][r][c] ----------------
__global__ void k_transpose_cast(const float* __restrict__ src, unsigned short* __restrict__ dst,
                                 int R, int C) {
    __shared__ float tile[64][65];
    const float* s = src + (long long)blockIdx.z * R * C;
    unsigned short* d = dst + (long long)blockIdx.z * R * C;
    const int r0 = blockIdx.x * 64, c0 = blockIdx.y * 64;
    const int tid = threadIdx.x;
#pragma unroll
    for (int i = 0; i < 16; ++i) {
        int e = i * 256 + tid;
        int rr = e >> 6, cc = e & 63;
        tile[rr][cc] = s[(long long)(r0 + rr) * C + (c0 + cc)];
    }
    __syncthreads();
#pragma unroll
    for (int i = 0; i < 16; ++i) {
        int e = i * 256 + tid;
        int orr = e >> 6, occ = e & 63;
        d[(long long)(c0 + orr) * R + (r0 + occ)] = f2bf(tile[occ][orr]);
    }
}

// ---------------- ctx GEMM: ctx[n] = bm + sum_t feats_b[nidx[n,t]] @ WmT[t] ----------------
// block = 512 thr (8 waves, 2Mx4N), tile 128(M) x 256(N), wave tile 64x64.
// A (gathered rows) staged into LDS via gathered global_load_lds, double-buffered.
// Swizzle (rule 21): LDS dest linear; global SOURCE 16B-unit u -> u ^ (row&7);
// reads apply the same XOR. B direct from L2 (wmt 4MB, hot).
__global__ __launch_bounds__(512, 4) void k_ctx(
    const unsigned short* __restrict__ feats_b,   // (NPTS+1) x 128
    const int* __restrict__ nidx_t,               // TAPS x NP2
    const unsigned short* __restrict__ wmt,       // 62 x 256 x 128
    const float* __restrict__ bm,                 // 256
    unsigned short* __restrict__ ctx_b)           // NP2 x 256 (bf16)
{
    __shared__ unsigned short albuf[2][128 * 128];   // 2 x 32KB

    const int m0 = blockIdx.x * 128;
    const int lane = threadIdx.x & 63;
    const int w = threadIdx.x >> 6;
    const int wr = w >> 2, wc = w & 3;
    const int wmL = wr * 64;                 // local M base of this wave
    const int wn0 = wc * 64;
    const int l15 = lane & 15, lk = lane >> 4;

    f32x4 acc[4][4] = {};

    int bcol[4];
#pragma unroll
    for (int nf = 0; nf < 4; ++nf) bcol[nf] = (wn0 + nf * 16 + l15) * 128 + lk * 8;

    // --- prologue: stage tap 0, prefetch indices for tap 1 ---
    int idxv[4];
#pragma unroll
    for (int i = 0; i < 4; ++i)
        idxv[i] = nidx_t[m0 + w * 16 + i * 4 + lk];
#pragma unroll
    for (int i = 0; i < 4; ++i) {
        const int xr = (i * 4 + lk) & 7;                       // row & 7
        const unsigned short* g = feats_b + (unsigned)idxv[i] * 128u + ((l15 ^ xr) << 3);
        gload_lds16(g, &albuf[0][(w * 16 + i * 4) * 128]);
    }
#pragma unroll
    for (int i = 0; i < 4; ++i)
        idxv[i] = nidx_t[(long long)1 * NP2 + m0 + w * 16 + i * 4 + lk];
    __syncthreads();

    for (int t = 0; t < TAPS; ++t) {
        const int buf = t & 1;
        if (t + 1 < TAPS) {
            // stage tap t+1 into buf^1 (indices prefetched last iter)
#pragma unroll
            for (int i = 0; i < 4; ++i) {
                const int xr = (i * 4 + lk) & 7;
                const unsigned short* g = feats_b + (unsigned)idxv[i] * 128u + ((l15 ^ xr) << 3);
                gload_lds16(g, &albuf[buf ^ 1][(w * 16 + i * 4) * 128]);
            }
            // prefetch indices for tap t+2
            const int tt = (t + 2 < TAPS) ? t + 2 : TAPS - 1;
#pragma unroll
            for (int i = 0; i < 4; ++i)
                idxv[i] = nidx_t[(long long)tt * NP2 + m0 + w * 16 + i * 4 + lk];
        }
        // compute tap t from albuf[buf]
        const unsigned short* wt = wmt + t * (256 * 128);
#pragma unroll
        for (int ks = 0; ks < 4; ++ks) {
            bf16x8 a[4], b[4];
#pragma unroll
            for (int mf = 0; mf < 4; ++mf) {
                const int r = wmL + mf * 16 + l15;
                const int u = ks * 4 + lk;
                a[mf] = *reinterpret_cast<const bf16x8*>(
                    &albuf[buf][r * 128 + ((u ^ (l15 & 7)) << 3)]);
            }
#pragma unroll
            for (int nf = 0; nf < 4; ++nf) b[nf] = ld8(wt + bcol[nf] + ks * 32);
#pragma unroll
            for (int mf = 0; mf < 4; ++mf)
#pragma unroll
                for (int nf = 0; nf < 4; ++nf)
                    acc[mf][nf] = __builtin_amdgcn_mfma_f32_16x16x32_bf16(a[mf], b[nf], acc[mf][nf], 0, 0, 0);
        }
        __syncthreads();   // drains vmcnt(0): staged tap t+1 complete; buf reads done
    }

    // epilogue: + bm, store bf16 (all NP2 rows valid).  C/D: col=lane&15, row=(lane>>4)*4+j
#pragma unroll
    for (int nf = 0; nf < 4; ++nf) {
        int col = wn0 + nf * 16 + l15;
        float bias = bm[col];
#pragma unroll
        for (int mf = 0; mf < 4; ++mf) {
#pragma unroll
            for (int j = 0; j < 4; ++j) {
                int gr = m0 + wmL + mf * 16 + lk * 4 + j;
                ctx_b[(long long)gr * 256 + col] = f2bf(acc[mf][nf][j] + bias);
            }
        }
    }
}

// ---------------- MLP: out = (relu(relu(ctx@W0+b0)@W1+b1))@W2+b2 ; split loc / |scale| ----------------
__global__ __launch_bounds__(512) void k_mlp(
    const unsigned short* __restrict__ ctx_b,
    const unsigned short* __restrict__ w0t, const float* __restrict__ b0,
    const unsigned short* __restrict__ w1t, const float* __restrict__ b1,
    const unsigned short* __restrict__ w2t, const float* __restrict__ b2,
    float* __restrict__ out)
{
    __shared__ unsigned short hbuf[128 * 256];
    const int m0 = blockIdx.x * 128;
    const int lane = threadIdx.x & 63;
    const int w = threadIdx.x >> 6;
    const int wr = w >> 2, wc = w & 3;
    const int l15 = lane & 15, lk = lane >> 4;
    const int wn0 = wc * 64;
    const int lm0 = wr * 64;
    const int wm0 = m0 + lm0;

    f32x4 acc[4][4];

    // ---- layer 1: A = ctx_b (global), B = w0t
#pragma unroll
    for (int i = 0; i < 4; ++i)
#pragma unroll
        for (int j = 0; j < 4; ++j) acc[i][j] = (f32x4){0.f, 0.f, 0.f, 0.f};
#pragma unroll
    for (int ks = 0; ks < 8; ++ks) {
        bf16x8 a[4], b[4];
#pragma unroll
        for (int mf = 0; mf < 4; ++mf)
            a[mf] = ld8(ctx_b + (long long)(wm0 + mf * 16 + l15) * 256 + lk * 8 + ks * 32);
#pragma unroll
        for (int nf = 0; nf < 4; ++nf)
            b[nf] = ld8(w0t + (wn0 + nf * 16 + l15) * 256 + lk * 8 + ks * 32);
#pragma unroll
        for (int mf = 0; mf < 4; ++mf)
#pragma unroll
            for (int nf = 0; nf < 4; ++nf)
                acc[mf][nf] = __builtin_amdgcn_mfma_f32_16x16x32_bf16(a[mf], b[nf], acc[mf][nf], 0, 0, 0);
    }
#pragma unroll
    for (int nf = 0; nf < 4; ++nf) {
        int col = wn0 + nf * 16 + l15;
        float bias = b0[col];
#pragma unroll
        for (int mf = 0; mf < 4; ++mf)
#pragma unroll
            for (int j = 0; j < 4; ++j) {
                int lr = lm0 + mf * 16 + lk * 4 + j;
                float v = fmaxf(acc[mf][nf][j] + bias, 0.f);
                int e = (lr * 256 + col) ^ ((lr & 7) << 3);
                hbuf[e] = f2bf(v);
            }
    }
    __syncthreads();

    // ---- layer 2: A = hbuf (swizzled), B = w1t
#pragma unroll
    for (int i = 0; i < 4; ++i)
#pragma unroll
        for (int j = 0; j < 4; ++j) acc[i][j] = (f32x4){0.f, 0.f, 0.f, 0.f};
#pragma unroll
    for (int ks = 0; ks < 8; ++ks) {
        bf16x8 a[4], b[4];
#pragma unroll
        for (int mf = 0; mf < 4; ++mf) {
            int lr = lm0 + mf * 16 + l15;
            int e = (lr * 256 + lk * 8 + ks * 32) ^ ((lr & 7) << 3);
            a[mf] = ld8(hbuf + e);
        }
#pragma unroll
        for (int nf = 0; nf < 4; ++nf)
            b[nf] = ld8(w1t + (wn0 + nf * 16 + l15) * 256 + lk * 8 + ks * 32);
#pragma unroll
        for (int mf = 0; mf < 4; ++mf)
#pragma unroll
            for (int nf = 0; nf < 4; ++nf)
                acc[mf][nf] = __builtin_amdgcn_mfma_f32_16x16x32_bf16(a[mf], b[nf], acc[mf][nf], 0, 0, 0);
    }
    __syncthreads();
#pragma unroll
    for (int nf = 0; nf < 4; ++nf) {
        int col = wn0 + nf * 16 + l15;
        float bias = b1[col];
#pragma unroll
        for (int mf = 0; mf < 4; ++mf)
#pragma unroll
            for (int j = 0; j < 4; ++j) {
                int lr = lm0 + mf * 16 + lk * 4 + j;
                float v = fmaxf(acc[mf][nf][j] + bias, 0.f);
                int e = (lr * 256 + col) ^ ((lr & 7) << 3);
                hbuf[e] = f2bf(v);
            }
    }
    __syncthreads();

    // ---- layer 3: A = hbuf, B = w2t, write outputs
#pragma unroll
    for (int i = 0; i < 4; ++i)
#pragma unroll
        for (int j = 0; j < 4; ++j) acc[i][j] = (f32x4){0.f, 0.f, 0.f, 0.f};
#pragma unroll
    for (int ks = 0; ks < 8; ++ks) {
        bf16x8 a[4], b[4];
#pragma unroll
        for (int mf = 0; mf < 4; ++mf) {
            int lr = lm0 + mf * 16 + l15;
            int e = (lr * 256 + lk * 8 + ks * 32) ^ ((lr & 7) << 3);
            a[mf] = ld8(hbuf + e);
        }
#pragma unroll
        for (int nf = 0; nf < 4; ++nf)
            b[nf] = ld8(w2t + (wn0 + nf * 16 + l15) * 256 + lk * 8 + ks * 32);
#pragma unroll
        for (int mf = 0; mf < 4; ++mf)
#pragma unroll
            for (int nf = 0; nf < 4; ++nf)
                acc[mf][nf] = __builtin_amdgcn_mfma_f32_16x16x32_bf16(a[mf], b[nf], acc[mf][nf], 0, 0, 0);
    }
#pragma unroll
    for (int nf = 0; nf < 4; ++nf) {
        int col = wn0 + nf * 16 + l15;
        float bias = b2[col];
#pragma unroll
        for (int mf = 0; mf < 4; ++mf)
#pragma unroll
            for (int j = 0; j < 4; ++j) {
                int gr = wm0 + mf * 16 + lk * 4 + j;
                if (gr < NPTS) {
                    float v = acc[mf][nf][j] + bias;
                    if (col < 128) out[(long long)gr * 128 + col] = v;
                    else out[(long long)NPTS * 128 + (long long)gr * 128 + (col - 128)] = fabsf(v);
                }
            }
    }
}

extern "C" void kernel_launch(void* const* d_in, const int* in_sizes, int n_in,
                              void* d_out, int out_size, void* d_ws, size_t ws_size,
                              hipStream_t stream) {
    const float* feats = (const float*)d_in[0];
    const int*   nidx  = (const int*)d_in[1];
    const float* Wm    = (const float*)d_in[2];
    const float* bm    = (const float*)d_in[3];
    const float* W0    = (const float*)d_in[4];
    const float* b0    = (const float*)d_in[5];
    const float* W1    = (const float*)d_in[6];
    const float* b1    = (const float*)d_in[7];
    const float* W2    = (const float*)d_in[8];
    const float* b2    = (const float*)d_in[9];

    char* ws = (char*)d_ws;
    size_t o = 0;
    unsigned short* feats_b = (unsigned short*)(ws + o); o += (size_t)(NPTS + 1) * CIN * 2;
    o = (o + 255) & ~(size_t)255;
    unsigned short* wmt = (unsigned short*)(ws + o); o += (size_t)TAPS * 256 * 128 * 2;
    unsigned short* w0t = (unsigned short*)(ws + o); o += 256 * 256 * 2;
    unsigned short* w1t = (unsigned short*)(ws + o); o += 256 * 256 * 2;
    unsigned short* w2t = (unsigned short*)(ws + o); o += 256 * 256 * 2;
    int* nidx_t = (int*)(ws + o); o += (size_t)TAPS * NP2 * 4;
    unsigned short* ctx_b = (unsigned short*)(ws + o); o += (size_t)NP2 * 256 * 2;

    k_cast_feats<<<2048, 256, 0, stream>>>(feats, feats_b);
    k_nidx_t<<<(NP2 + 255) / 256, 256, 0, stream>>>(nidx, nidx_t);
    k_transpose_cast<<<dim3(2, 4, TAPS), 256, 0, stream>>>(Wm, wmt, 128, 256);
    k_transpose_cast<<<dim3(4, 4, 1), 256, 0, stream>>>(W0, w0t, 256, 256);
    k_transpose_cast<<<dim3(4, 4, 1), 256, 0, stream>>>(W1, w1t, 256, 256);
    k_transpose_cast<<<dim3(4, 4, 1), 256, 0, stream>>>(W2, w2t, 256, 256);
    k_ctx<<<NP2 / 128, 512, 0, stream>>>(feats_b, nidx_t, wmt, bm, ctx_b);
    k_mlp<<<NP2 / 128, 512, 0, stream>>>(ctx_b, w0t, b0, w1t, b1, w2t, b2, (float*)d_out);
}